// Round 1
// 1100.880 us; speedup vs baseline: 1.0448x; 1.0448x over previous
//
#include <hip/hip_runtime.h>
#include <math.h>

typedef __attribute__((ext_vector_type(8))) short short8;
typedef __attribute__((ext_vector_type(4))) float f32x4;

__device__ __forceinline__ unsigned short bf16_rne(float f) {
  union { float f; unsigned u; } x; x.f = f;
  unsigned r = x.u + 0x7FFFu + ((x.u >> 16) & 1u);
  return (unsigned short)(r >> 16);
}

__device__ __forceinline__ float gelu_f(float x) {
  float z = 0.7978845608028654f * (x + 0.044715f * x * x * x);
  z = fminf(fmaxf(z, -15.f), 15.f);
  float e = __expf(2.f * z);
  float th = (e - 1.f) / (e + 1.f);
  return 0.5f * x * (1.f + th);
}

__device__ __forceinline__ float softplus_f(float x) {
  return (x > 15.f) ? x : log1pf(__expf(x));
}

__device__ __forceinline__ float wave_sum(float v) {
  #pragma unroll
  for (int off = 32; off > 0; off >>= 1) v += __shfl_down(v, off, 64);
  return v;
}

// ---------------- fused proj (one wave per row) + conv-weight bf16 transpose
__global__ __launch_bounds__(256) void pre_kern(
    const float* __restrict__ x, const float* __restrict__ w,
    const float* __restrict__ b, const float* __restrict__ s,
    const float* __restrict__ o, unsigned short* __restrict__ h0bf,
    const float* __restrict__ cw, unsigned short* __restrict__ cwT)
{
  if (blockIdx.x >= 2048) {
    // cvtw: cw[tap][ci][co] fp32 -> cwT[tap][co][ci] bf16
    int e = (blockIdx.x - 2048) * 256 + threadIdx.x;   // 294912 total
    int co = e % 192, rest = e / 192;
    int ci = rest % 96, tap = rest / 96;
    cwT[((size_t)tap * 192 + co) * 96 + ci] = bf16_rne(cw[e]);
    return;
  }
  int t = threadIdx.x, wave = t >> 6, l = t & 63;
  size_t row = (size_t)blockIdx.x * 4 + wave;
  const float* xr = x + row * 32;
  bool has2 = (l < 32);
  int c1 = l, c2 = has2 ? 64 + l : 0;
  float v1 = b[c1], v2 = b[c2];
  #pragma unroll
  for (int k = 0; k < 32; ++k) {
    float xv = xr[k];
    v1 += xv * w[k * 96 + c1];
    v2 += xv * w[k * 96 + c2];
  }
  if (!has2) v2 = 0.f;
  float sum = wave_sum(v1 + v2);
  float ssq = wave_sum(v1 * v1 + v2 * v2);
  sum = __shfl(sum, 0, 64); ssq = __shfl(ssq, 0, 64);
  float mu = sum / 96.f, var = ssq / 96.f - mu * mu;
  float inv = rsqrtf(var + 1e-5f);
  float f1 = gelu_f((v1 - mu) * inv * s[c1] + o[c1]);
  h0bf[row * 96 + c1] = bf16_rne(f1);
  if (has2) {
    float f2 = gelu_f((v2 - mu) * inv * s[c2] + o[c2]);
    h0bf[row * 96 + c2] = bf16_rne(f2);
  }
}

// ---------------- conv 4x4 SAME via 16 shifted MFMA GEMMs, bf16 weights
__global__ __launch_bounds__(256) void conv_kern(
    const unsigned short* __restrict__ h0bf, const unsigned short* __restrict__ cwT,
    const float* __restrict__ cb, float* __restrict__ y)
{
  __shared__ unsigned short As[12 * 64 * 8];
  __shared__ unsigned short Ws[12 * 64 * 8];
  int t = threadIdx.x;
  int i = blockIdx.x;
  int n0 = blockIdx.y * 64;
  int wave = t >> 6, lane = t & 63, quad = lane >> 4, l16 = lane & 15;
  f32x4 zero4 = {0.f, 0.f, 0.f, 0.f};
  f32x4 acc[4];
  #pragma unroll
  for (int nt = 0; nt < 4; ++nt) acc[nt] = zero4;
  for (int tap = 0; tap < 16; ++tap) {
    int kh = tap >> 2, kw = tap & 3;
    int si = i + kh - 1;
    if (si < 0 || si >= 128) continue;
    {
      int j = t & 63, g = t >> 6;
      int sj = j + kw - 1;
      bool ok = (sj >= 0 && sj < 64);
      #pragma unroll
      for (int q = 0; q < 3; ++q) {
        int kb = g + 4 * q;
        short8 v = {0,0,0,0,0,0,0,0};
        if (ok) v = *(const short8*)(h0bf + (size_t)(si * 64 + sj) * 96 + kb * 8);
        *(short8*)(As + (kb * 64 + j) * 8) = v;
      }
    }
    {
      int n = t & 63, g = t >> 6;
      #pragma unroll
      for (int q = 0; q < 3; ++q) {
        int kb = g + 4 * q;
        *(short8*)(Ws + (kb * 64 + n) * 8) =
            *(const short8*)(cwT + ((size_t)tap * 192 + n0 + n) * 96 + kb * 8);
      }
    }
    __syncthreads();
    #pragma unroll
    for (int ks = 0; ks < 3; ++ks) {
      int kbq = ks * 4 + quad;
      short8 a = *(const short8*)(As + (kbq * 64 + wave * 16 + l16) * 8);
      #pragma unroll
      for (int nt = 0; nt < 4; ++nt) {
        short8 b = *(const short8*)(Ws + (kbq * 64 + nt * 16 + l16) * 8);
        acc[nt] = __builtin_amdgcn_mfma_f32_16x16x32_bf16(a, b, acc[nt], 0, 0, 0);
      }
    }
    __syncthreads();
  }
  #pragma unroll
  for (int nt = 0; nt < 4; ++nt) {
    int col = n0 + nt * 16 + l16;
    float bv = cb[col];
    #pragma unroll
    for (int r = 0; r < 4; ++r) {
      int row = wave * 16 + quad * 4 + r;
      y[(size_t)(i * 64 + row) * 192 + col] = acc[nt][r] + bv;
    }
  }
}

// ---------------- LN(192)+gelu: one wave per row, no barriers
__global__ __launch_bounds__(256) void ln_act_kern(
    const float* __restrict__ y, const float* __restrict__ res,
    const float* __restrict__ s, const float* __restrict__ o,
    float* __restrict__ h32, unsigned short* __restrict__ hbf)
{
  int t = threadIdx.x, wave = t >> 6, l = t & 63;
  size_t base = ((size_t)blockIdx.x * 4 + wave) * 192;
  float v0 = y[base + l], v1 = y[base + 64 + l], v2 = y[base + 128 + l];
  if (res) { v0 += res[base + l]; v1 += res[base + 64 + l]; v2 += res[base + 128 + l]; }
  float sum = wave_sum(v0 + v1 + v2);
  float ssq = wave_sum(v0 * v0 + v1 * v1 + v2 * v2);
  sum = __shfl(sum, 0, 64); ssq = __shfl(ssq, 0, 64);
  float mu = sum * (1.f / 192.f);
  float var = ssq * (1.f / 192.f) - mu * mu;
  float inv = rsqrtf(var + 1e-5f);
  float f0 = gelu_f((v0 - mu) * inv * s[l] + o[l]);
  float f1 = gelu_f((v1 - mu) * inv * s[64 + l] + o[64 + l]);
  float f2 = gelu_f((v2 - mu) * inv * s[128 + l] + o[128 + l]);
  h32[base + l] = f0; h32[base + 64 + l] = f1; h32[base + 128 + l] = f2;
  hbf[base + l] = bf16_rne(f0); hbf[base + 64 + l] = bf16_rne(f1); hbf[base + 128 + l] = bf16_rne(f2);
}

// ---------------- fused per-layer: qkv+mass GEMM -> QQ^T -> softmax -> AV
// grid = 256 blocks: (b = bx>>1, half = bx&1); 4 waves = 4 local heads.
// LDS plan (dynamic, 67584 B):
//   phase 1: A_bf @0 (24576), Wt @24576 (26624)
//   phase>=2: qk_lds @0 (16384), v_lds @16384 (16384), w_bf @32768 (32768),
//             mm @65536 (1024), sq @66560 (1024)
__device__ __forceinline__ void stage_w(
    unsigned short* Wt, const float* qw, const float* vw, const float* mw,
    int half, int k0, int t)
{
  for (int c = t; c < 1664; c += 256) {   // chunk = kb*208 + n
    int kb = c / 208, n = c - kb * 208;
    short8 v8;
    if (n < 192) {
      const float* src = (n < 96) ? (qw + half * 96 + n) : (vw + half * 96 + n - 96);
      #pragma unroll
      for (int jj = 0; jj < 8; ++jj)
        v8[jj] = (short)bf16_rne(src[(size_t)(k0 + kb * 8 + jj) * 192]);
    } else if (n < 196) {
      const float* src = mw + half * 4 + (n - 192);
      #pragma unroll
      for (int jj = 0; jj < 8; ++jj)
        v8[jj] = (short)bf16_rne(src[(size_t)(k0 + kb * 8 + jj) * 8]);
    } else {
      v8 = (short8){0,0,0,0,0,0,0,0};
    }
    *(short8*)(Wt + c * 8) = v8;
  }
}

__global__ __launch_bounds__(256) void layer_attn(
    const unsigned short* __restrict__ hbf,
    const float* __restrict__ qw, const float* __restrict__ qb,
    const float* __restrict__ vw, const float* __restrict__ vb,
    const float* __restrict__ mw, const float* __restrict__ mb,
    float* __restrict__ att)
{
  extern __shared__ char smem[];
  unsigned short* qk_lds = (unsigned short*)smem;             // [4h][4kb_d][64s][8]
  unsigned short* v_ldsp = (unsigned short*)(smem + 16384);   // [4h][8kb_s][32d][8]
  unsigned short* w_bfp  = (unsigned short*)(smem + 32768);   // [4h][8kb_sj][64si][8]
  float* mmp = (float*)(smem + 65536);                        // [64s][4h]
  float* sqp = (float*)(smem + 66560);                        // [4h][64]
  unsigned short* A_bf = (unsigned short*)smem;               // [24kb][64m][8]
  unsigned short* Wt   = (unsigned short*)(smem + 24576);     // [8kb][208n][8]

  int t = threadIdx.x;
  int bb = blockIdx.x >> 1, half = blockIdx.x & 1;
  int wv = t >> 6, lane = t & 63, quad = lane >> 4, l16 = lane & 15;

  // ---- phase 0/1: stage A (64x192 bf16) and W tiles; GEMM 64x208x192
  for (int c = t; c < 1536; c += 256) {
    int kb = c >> 6, m = c & 63;
    *(short8*)(A_bf + c * 8) =
        *(const short8*)(hbf + ((size_t)bb * 64 + m) * 192 + kb * 8);
  }
  stage_w(Wt, qw, vw, mw, half, 0, t);
  __syncthreads();
  f32x4 acc[13];
  #pragma unroll
  for (int i = 0; i < 13; ++i) acc[i] = (f32x4){0.f,0.f,0.f,0.f};
  for (int kt = 0; kt < 3; ++kt) {
    #pragma unroll
    for (int ks = 0; ks < 2; ++ks) {
      int kq = ks * 4 + quad;
      short8 a = *(const short8*)(A_bf + ((kt * 8 + kq) * 64 + wv * 16 + l16) * 8);
      #pragma unroll
      for (int nt = 0; nt < 13; ++nt) {
        short8 b = *(const short8*)(Wt + (kq * 208 + nt * 16 + l16) * 8);
        acc[nt] = __builtin_amdgcn_mfma_f32_16x16x32_bf16(a, b, acc[nt], 0, 0, 0);
      }
    }
    if (kt < 2) {
      __syncthreads();
      stage_w(Wt, qw, vw, mw, half, (kt + 1) * 64, t);
      __syncthreads();
    }
  }
  __syncthreads();   // A_bf/Wt dead; regions reused below

  // ---- phase 2: scatter acc -> qk_lds (bf16, zero-pad d=24..31), v_lds, mass
  {
    int zh = t >> 6, zs = t & 63;   // zero qk pad block kb_d = 3
    *(short8*)(qk_lds + ((zh * 4 + 3) * 64 + zs) * 8) = (short8){0,0,0,0,0,0,0,0};
  }
  int row = wv * 16 + quad * 4;
  #pragma unroll
  for (int nt = 0; nt < 6; ++nt) {        // qk columns 0..95 of this half
    int n = nt * 16 + l16;
    int hl = n / 24, d = n - hl * 24;
    float bqv = qb[half * 96 + n];
    #pragma unroll
    for (int r = 0; r < 4; ++r)
      qk_lds[((hl * 4 + (d >> 3)) * 64 + row + r) * 8 + (d & 7)] =
          bf16_rne(acc[nt][r] + bqv);
  }
  #pragma unroll
  for (int nt = 0; nt < 6; ++nt) {        // v columns 0..95 of this half
    int n = nt * 16 + l16;
    int hl = n / 24, d = n - hl * 24;
    float bvv = vb[half * 96 + n];
    #pragma unroll
    for (int r = 0; r < 4; ++r) {
      int sidx = row + r;
      v_ldsp[((hl * 8 + (sidx >> 3)) * 32 + d) * 8 + (sidx & 7)] =
          bf16_rne(acc[nt + 6][r] + bvv);
    }
  }
  if (l16 < 4) {                          // mass (4 local heads)
    float mbv = mb[half * 4 + l16];
    #pragma unroll
    for (int r = 0; r < 4; ++r)
      mmp[(row + r) * 4 + l16] = softplus_f(acc[12][r] + mbv);
  }
  __syncthreads();

  // ---- phase 3: per-wave head: S = QQ^T (K=24 pad 32), scores, softmax in regs
  const unsigned short* qh = qk_lds + (wv * 4) * 64 * 8;
  short8 frag[4];
  #pragma unroll
  for (int x2 = 0; x2 < 4; ++x2)
    frag[x2] = *(const short8*)(qh + (quad * 64 + x2 * 16 + l16) * 8);
  f32x4 s16[4][4];
  #pragma unroll
  for (int mt = 0; mt < 4; ++mt)
    #pragma unroll
    for (int nt = 0; nt < 4; ++nt)
      s16[mt][nt] = __builtin_amdgcn_mfma_f32_16x16x32_bf16(
          frag[mt], frag[nt], (f32x4){0.f,0.f,0.f,0.f}, 0, 0, 0);
  // diagonal of S is |q_i|^2 — write to sq for row/col broadcast
  float* sqh = sqp + wv * 64;
  #pragma unroll
  for (int mt = 0; mt < 4; ++mt)
    #pragma unroll
    for (int r = 0; r < 4; ++r)
      if (l16 == quad * 4 + r) sqh[mt * 16 + l16] = s16[mt][mt][r];
  __syncthreads();
  f32x4 sqr[4], mr[4];
  float sqc[4], mc[4];
  #pragma unroll
  for (int mt = 0; mt < 4; ++mt) {
    sqr[mt] = *(const f32x4*)(sqh + mt * 16 + quad * 4);
    #pragma unroll
    for (int r = 0; r < 4; ++r) mr[mt][r] = mmp[(mt * 16 + quad * 4 + r) * 4 + wv];
  }
  #pragma unroll
  for (int nt = 0; nt < 4; ++nt) {
    sqc[nt] = sqh[nt * 16 + l16];
    mc[nt]  = mmp[(nt * 16 + l16) * 4 + wv];
  }
  #pragma unroll
  for (int mt = 0; mt < 4; ++mt)
    #pragma unroll
    for (int nt = 0; nt < 4; ++nt)
      #pragma unroll
      for (int r = 0; r < 4; ++r) {
        float d2 = fmaxf(sqr[mt][r] + sqc[nt] - 2.f * s16[mt][nt][r], 0.f) + 1e-6f;
        s16[mt][nt][r] = mr[mt][r] * mc[nt] / d2;
      }
  f32x4 inv4[4];
  #pragma unroll
  for (int mt = 0; mt < 4; ++mt)
    #pragma unroll
    for (int r = 0; r < 4; ++r) {
      float mx = fmaxf(fmaxf(s16[mt][0][r], s16[mt][1][r]),
                       fmaxf(s16[mt][2][r], s16[mt][3][r]));
      #pragma unroll
      for (int off = 1; off < 16; off <<= 1) mx = fmaxf(mx, __shfl_xor(mx, off, 64));
      float sm = 0.f;
      #pragma unroll
      for (int nt = 0; nt < 4; ++nt) {
        float e = __expf(s16[mt][nt][r] - mx);
        s16[mt][nt][r] = e;
        sm += e;
      }
      #pragma unroll
      for (int off = 1; off < 16; off <<= 1) sm += __shfl_xor(sm, off, 64);
      inv4[mt][r] = 1.f / sm;
    }

  // ---- phase 4: P (bf16) -> LDS in AV A-operand layout
  unsigned short* wb = w_bfp + wv * (8 * 64 * 8);
  #pragma unroll
  for (int mt = 0; mt < 4; ++mt)
    #pragma unroll
    for (int nt = 0; nt < 4; ++nt)
      #pragma unroll
      for (int r = 0; r < 4; ++r) {
        int si = mt * 16 + quad * 4 + r, sj = nt * 16 + l16;
        wb[((sj >> 3) * 64 + si) * 8 + (sj & 7)] = bf16_rne(s16[mt][nt][r]);
      }
  __syncthreads();

  // ---- phase 5: O = P @ V (K=64), scale by 1/rowsum, store
  const unsigned short* vh = v_ldsp + wv * (8 * 32 * 8);
  f32x4 o2[4][2];
  #pragma unroll
  for (int mt = 0; mt < 4; ++mt)
    #pragma unroll
    for (int nt = 0; nt < 2; ++nt) o2[mt][nt] = (f32x4){0.f,0.f,0.f,0.f};
  #pragma unroll
  for (int ks = 0; ks < 2; ++ks) {
    int kq = ks * 4 + quad;
    short8 aw[4], bv2[2];
    #pragma unroll
    for (int mt = 0; mt < 4; ++mt)
      aw[mt] = *(const short8*)(wb + (kq * 64 + mt * 16 + l16) * 8);
    #pragma unroll
    for (int nt = 0; nt < 2; ++nt)
      bv2[nt] = *(const short8*)(vh + (kq * 32 + nt * 16 + l16) * 8);
    #pragma unroll
    for (int mt = 0; mt < 4; ++mt)
      #pragma unroll
      for (int nt = 0; nt < 2; ++nt)
        o2[mt][nt] = __builtin_amdgcn_mfma_f32_16x16x32_bf16(aw[mt], bv2[nt], o2[mt][nt], 0, 0, 0);
  }
  int hg = half * 4 + wv;
  size_t obase = ((size_t)bb * 64) * 192 + hg * 24;
  #pragma unroll
  for (int mt = 0; mt < 4; ++mt)
    #pragma unroll
    for (int nt = 0; nt < 2; ++nt) {
      int col = nt * 16 + l16;
      if (col < 24) {
        #pragma unroll
        for (int r = 0; r < 4; ++r) {
          int sidx = mt * 16 + quad * 4 + r;
          att[obase + (size_t)sidx * 192 + col] = o2[mt][nt][r] * inv4[mt][r];
        }
      }
    }
}

// ---------------- generic small MFMA GEMM (mlp1 / mlp2+residual)
__global__ __launch_bounds__(256) void gemm_small(
    const unsigned short* __restrict__ A, int lda,
    const float* __restrict__ W, int ldw,
    const float* __restrict__ bias, const float* __restrict__ res,
    float* __restrict__ outF, unsigned short* __restrict__ outB,
    int K, int ldo, int act)
{
  __shared__ unsigned short As[8 * 64 * 8];
  __shared__ unsigned short Ws[8 * 64 * 8];
  int t = threadIdx.x;
  int m0 = blockIdx.x * 64, n0 = blockIdx.y * 64;
  int wave = t >> 6, lane = t & 63, quad = lane >> 4, l16 = lane & 15;
  f32x4 zero4 = {0.f, 0.f, 0.f, 0.f};
  f32x4 acc[4];
  #pragma unroll
  for (int nt = 0; nt < 4; ++nt) acc[nt] = zero4;
  for (int k0 = 0; k0 < K; k0 += 64) {
    {
      int kb = t & 7, m = t >> 3;
      #pragma unroll
      for (int r = 0; r < 2; ++r) {
        int mm = m + r * 32;
        *(short8*)(As + (kb * 64 + mm) * 8) =
            *(const short8*)(A + (size_t)(m0 + mm) * lda + k0 + kb * 8);
      }
    }
    {
      int n = t & 63, g = t >> 6;
      #pragma unroll
      for (int q = 0; q < 2; ++q) {
        int kb = g + 4 * q;
        short8 v;
        #pragma unroll
        for (int jj = 0; jj < 8; ++jj)
          v[jj] = (short)bf16_rne(W[(size_t)(k0 + kb * 8 + jj) * ldw + n0 + n]);
        *(short8*)(Ws + (kb * 64 + n) * 8) = v;
      }
    }
    __syncthreads();
    #pragma unroll
    for (int ks = 0; ks < 2; ++ks) {
      short8 a = *(const short8*)(As + ((ks * 4 + quad) * 64 + wave * 16 + l16) * 8);
      #pragma unroll
      for (int nt = 0; nt < 4; ++nt) {
        short8 b = *(const short8*)(Ws + ((ks * 4 + quad) * 64 + nt * 16 + l16) * 8);
        acc[nt] = __builtin_amdgcn_mfma_f32_16x16x32_bf16(a, b, acc[nt], 0, 0, 0);
      }
    }
    __syncthreads();
  }
  #pragma unroll
  for (int nt = 0; nt < 4; ++nt) {
    int col = n0 + nt * 16 + l16;
    float bv = bias[col];
    #pragma unroll
    for (int r = 0; r < 4; ++r) {
      int row = m0 + wave * 16 + quad * 4 + r;
      float v = acc[nt][r] + bv;
      if (act) v = gelu_f(v);
      if (res) v += res[(size_t)row * ldo + col];
      if (outF) outF[(size_t)row * ldo + col] = v;
      if (outB) outB[(size_t)row * ldo + col] = bf16_rne(v);
    }
  }
}

// ---------------- fc: (128 x 12288) @ (12288 x 12288), split-K=4, BN=64
// Register-prefetched pipeline: next A/W tiles issued before the MFMA cluster.
__global__ __launch_bounds__(256) void gemm_fc(
    const unsigned short* __restrict__ A, const float* __restrict__ W,
    float* __restrict__ part)
{
  __shared__ unsigned short As[8 * 128 * 8];   // 16 KB
  __shared__ unsigned short Bs[8 * 64 * 8];    // 8 KB
  int t = threadIdx.x;
  int n0 = blockIdx.x * 64;
  int split = blockIdx.y;
  int wave = t >> 6, lane = t & 63, quad = lane >> 4, l16 = lane & 15;
  int wm = wave * 32;
  int a_kb = t & 7, a_m = t >> 3;
  int w_n4 = t & 15, w_kr = t >> 4;
  f32x4 zero4 = {0.f, 0.f, 0.f, 0.f};
  f32x4 acc[2][4];
  #pragma unroll
  for (int mt = 0; mt < 2; ++mt)
    #pragma unroll
    for (int nt = 0; nt < 4; ++nt) acc[mt][nt] = zero4;
  int kk = split * 3072;
  short8 aR[4]; f32x4 wR[4];
  #pragma unroll
  for (int r = 0; r < 4; ++r)
    aR[r] = *(const short8*)(A + (size_t)(a_m + r * 32) * 12288 + kk + a_kb * 8);
  #pragma unroll
  for (int r = 0; r < 4; ++r)
    wR[r] = *(const f32x4*)(W + (size_t)(kk + w_kr + 16 * r) * 12288 + n0 + w_n4 * 4);
  for (int it = 0; it < 48; ++it) {
    #pragma unroll
    for (int r = 0; r < 4; ++r)
      *(short8*)(As + (a_kb * 128 + a_m + r * 32) * 8) = aR[r];
    #pragma unroll
    for (int r = 0; r < 4; ++r) {
      int k = w_kr + 16 * r, kb = k >> 3, kj = k & 7;
      #pragma unroll
      for (int j = 0; j < 4; ++j)
        Bs[(kb * 64 + w_n4 * 4 + j) * 8 + kj] = bf16_rne(wR[r][j]);
    }
    __syncthreads();
    if (it < 47) {
      int kn = kk + 64;
      #pragma unroll
      for (int r = 0; r < 4; ++r)
        aR[r] = *(const short8*)(A + (size_t)(a_m + r * 32) * 12288 + kn + a_kb * 8);
      #pragma unroll
      for (int r = 0; r < 4; ++r)
        wR[r] = *(const f32x4*)(W + (size_t)(kn + w_kr + 16 * r) * 12288 + n0 + w_n4 * 4);
    }
    #pragma unroll
    for (int ks = 0; ks < 2; ++ks) {
      int kq = ks * 4 + quad;
      short8 a[2], b[4];
      #pragma unroll
      for (int mt = 0; mt < 2; ++mt)
        a[mt] = *(const short8*)(As + (kq * 128 + wm + mt * 16 + l16) * 8);
      #pragma unroll
      for (int nt = 0; nt < 4; ++nt)
        b[nt] = *(const short8*)(Bs + (kq * 64 + nt * 16 + l16) * 8);
      #pragma unroll
      for (int mt = 0; mt < 2; ++mt)
        #pragma unroll
        for (int nt = 0; nt < 4; ++nt)
          acc[mt][nt] = __builtin_amdgcn_mfma_f32_16x16x32_bf16(a[mt], b[nt], acc[mt][nt], 0, 0, 0);
    }
    __syncthreads();
    kk += 64;
  }
  float* po = part + (size_t)split * 128 * 12288;
  #pragma unroll
  for (int mt = 0; mt < 2; ++mt) {
    #pragma unroll
    for (int nt = 0; nt < 4; ++nt) {
      int col = n0 + nt * 16 + l16;
      #pragma unroll
      for (int r = 0; r < 4; ++r) {
        int row = wm + mt * 16 + quad * 4 + r;
        po[(size_t)row * 12288 + col] = acc[mt][nt][r];
      }
    }
  }
}

// ---------------- fused: split-K reduce + bias + gelu -> LDS -> LN(12288) -> out matmul
__global__ __launch_bounds__(256) void final_kern(
    const float* __restrict__ part, const float* __restrict__ fb,
    const float* __restrict__ s, const float* __restrict__ o,
    const float* __restrict__ ow, const float* __restrict__ ob,
    float* __restrict__ out)
{
  __shared__ float gls[12288];                  // 48 KB
  __shared__ float a1[4], a2[4];
  __shared__ float red[4][24];
  int m = blockIdx.x, t = threadIdx.x;
  const f32x4* p0 = (const f32x4*)(part + (size_t)m * 12288);
  const size_t S4 = (size_t)128 * 12288 / 4;    // split stride in f32x4
  float s1 = 0.f, s2 = 0.f;
  for (int k4 = t; k4 < 3072; k4 += 256) {
    f32x4 v = p0[k4] + p0[k4 + S4] + p0[k4 + 2 * S4] + p0[k4 + 3 * S4];
    f32x4 bb = *(const f32x4*)(fb + k4 * 4);
    f32x4 g;
    #pragma unroll
    for (int c = 0; c < 4; ++c) g[c] = gelu_f(v[c] + bb[c]);
    *(f32x4*)(gls + k4 * 4) = g;
    s1 += g[0] + g[1] + g[2] + g[3];
    s2 += g[0]*g[0] + g[1]*g[1] + g[2]*g[2] + g[3]*g[3];
  }
  s1 = wave_sum(s1); s2 = wave_sum(s2);
  int wv = t >> 6, ln = t & 63;
  if (ln == 0) { a1[wv] = s1; a2[wv] = s2; }
  __syncthreads();
  float sum = a1[0] + a1[1] + a1[2] + a1[3];
  float ssq = a2[0] + a2[1] + a2[2] + a2[3];
  float mu = sum / 12288.f, var = ssq / 12288.f - mu * mu;
  float inv = rsqrtf(var + 1e-5f);
  f32x4 acc6[6];
  #pragma unroll
  for (int j = 0; j < 6; ++j) acc6[j] = (f32x4){0.f,0.f,0.f,0.f};
  for (int k = t; k < 12288; k += 256) {
    float f = (gls[k] - mu) * inv * s[k] + o[k];
    const f32x4* owr = (const f32x4*)(ow + (size_t)k * 24);
    #pragma unroll
    for (int j = 0; j < 6; ++j) acc6[j] += f * owr[j];
  }
  #pragma unroll
  for (int j = 0; j < 6; ++j)
    #pragma unroll
    for (int c = 0; c < 4; ++c) {
      float v = wave_sum(acc6[j][c]);
      if (ln == 0) red[wv][j * 4 + c] = v;
    }
  __syncthreads();
  if (t < 24) out[m * 24 + t] = red[0][t] + red[1][t] + red[2][t] + red[3][t] + ob[t];
}

extern "C" void kernel_launch(void* const* d_in, const int* in_sizes, int n_in,
                              void* d_out, int out_size, void* d_ws, size_t ws_size,
                              hipStream_t stream) {
  const float* x      = (const float*)d_in[0];
  const float* proj_w = (const float*)d_in[1];
  const float* proj_b = (const float*)d_in[2];
  const float* ln0_s  = (const float*)d_in[3];
  const float* ln0_o  = (const float*)d_in[4];
  const float* conv_w = (const float*)d_in[5];
  const float* conv_b = (const float*)d_in[6];
  const float* ln1_s  = (const float*)d_in[7];
  const float* ln1_o  = (const float*)d_in[8];
  const float* qk_w   = (const float*)d_in[9];
  const float* qk_b   = (const float*)d_in[10];
  const float* mass_w = (const float*)d_in[11];
  const float* mass_b = (const float*)d_in[12];
  const float* v_w    = (const float*)d_in[13];
  const float* v_b    = (const float*)d_in[14];
  const float* norm_s = (const float*)d_in[15];
  const float* norm_o = (const float*)d_in[16];
  const float* mlp_w1 = (const float*)d_in[17];
  const float* mlp_b1 = (const float*)d_in[18];
  const float* mlp_w2 = (const float*)d_in[19];
  const float* mlp_b2 = (const float*)d_in[20];
  const float* fc_w   = (const float*)d_in[21];
  const float* fc_b   = (const float*)d_in[22];
  const float* ln2_s  = (const float*)d_in[23];
  const float* ln2_o  = (const float*)d_in[24];
  const float* out_w  = (const float*)d_in[25];
  const float* out_b  = (const float*)d_in[26];
  float* out = (float*)d_out;

  char* ws = (char*)d_ws;
  unsigned short* h0bf = (unsigned short*)(ws + 0);            // 1,572,864
  float* h32           = (float*)(ws + 1572864);               // 6,291,456
  unsigned short* hbf  = (unsigned short*)(ws + 7864320);      // 3,145,728
  unsigned short* cwT  = (unsigned short*)(ws + 11010048);     // 589,824
  char* sc = ws + 11599872;
  float* t_att = (float*)(sc + 12582912);                      // 6,291,456
  unsigned short* hid_bf = (unsigned short*)(sc + 18874368);   // 6,291,456
  float* partials = (float*)sc;   // 25.2 MB, aliases t_att/hid_bf (dead by fc)

  pre_kern<<<3200, 256, 0, stream>>>(x, proj_w, proj_b, ln0_s, ln0_o, h0bf,
                                     conv_w, cwT);
  conv_kern<<<dim3(128, 3), 256, 0, stream>>>(h0bf, cwT, conv_b, t_att);
  ln_act_kern<<<2048, 256, 0, stream>>>(t_att, nullptr, ln1_s, ln1_o, h32, hbf);
  for (int l = 0; l < 4; ++l) {
    layer_attn<<<256, 256, 67584, stream>>>(hbf,
        qk_w + l * 36864, qk_b + l * 192,
        v_w + l * 36864, v_b + l * 192,
        mass_w + l * 1536, mass_b + l * 8, t_att);
    ln_act_kern<<<2048, 256, 0, stream>>>(t_att, h32, norm_s + l * 192,
                                          norm_o + l * 192, h32, hbf);
  }
  gemm_small<<<dim3(128, 6), 256, 0, stream>>>(hbf, 192, mlp_w1, 384, mlp_b1,
      nullptr, (float*)nullptr, hid_bf, 192, 384, 1);
  gemm_small<<<dim3(128, 3), 256, 0, stream>>>(hid_bf, 384, mlp_w2, 192, mlp_b2,
      h32, h32, hbf, 384, 192, 0);
  gemm_fc<<<dim3(192, 4), 256, 0, stream>>>(hbf, fc_w, partials);
  final_kern<<<128, 256, 0, stream>>>(partials, fc_b, ln2_s, ln2_o, out_w, out_b, out);
}

// Round 2
// 1080.411 us; speedup vs baseline: 1.0646x; 1.0189x over previous
//
#include <hip/hip_runtime.h>
#include <math.h>

typedef __attribute__((ext_vector_type(8))) short short8;
typedef __attribute__((ext_vector_type(4))) float f32x4;

__device__ __forceinline__ unsigned short bf16_rne(float f) {
  union { float f; unsigned u; } x; x.f = f;
  unsigned r = x.u + 0x7FFFu + ((x.u >> 16) & 1u);
  return (unsigned short)(r >> 16);
}

__device__ __forceinline__ float gelu_f(float x) {
  float z = 0.7978845608028654f * (x + 0.044715f * x * x * x);
  z = fminf(fmaxf(z, -15.f), 15.f);
  float e = __expf(2.f * z);
  float th = (e - 1.f) / (e + 1.f);
  return 0.5f * x * (1.f + th);
}

__device__ __forceinline__ float softplus_f(float x) {
  return (x > 15.f) ? x : log1pf(__expf(x));
}

__device__ __forceinline__ float wave_sum(float v) {
  #pragma unroll
  for (int off = 32; off > 0; off >>= 1) v += __shfl_down(v, off, 64);
  return v;
}

// ---------------- fused: proj + all one-time weight conversions
// blocks [0,2048): proj rows; [2048,3200): conv w; [3200,4448): qkv+mass w;
// [4448,4736): mlp1 w; [4736,5024): mlp2 w
__global__ __launch_bounds__(256) void pre_kern(
    const float* __restrict__ x, const float* __restrict__ w,
    const float* __restrict__ b, const float* __restrict__ s,
    const float* __restrict__ o, unsigned short* __restrict__ h0bf,
    const float* __restrict__ cw, unsigned short* __restrict__ cwT,
    const float* __restrict__ qk_w, const float* __restrict__ v_w,
    const float* __restrict__ mass_w, unsigned short* __restrict__ wqkvT,
    const float* __restrict__ mlp_w1, unsigned short* __restrict__ wm1T,
    const float* __restrict__ mlp_w2, unsigned short* __restrict__ wm2T)
{
  int t = threadIdx.x;
  int bx = blockIdx.x;
  if (bx >= 2048) {
    bx -= 2048;
    if (bx < 1152) {
      // cvtw: cw[tap][ci][co] fp32 -> cwT[tap][co][ci] bf16
      int e = bx * 256 + t;                       // 294912
      int co = e % 192, rest = e / 192;
      int ci = rest % 96, tap = rest / 96;
      cwT[((size_t)tap * 192 + co) * 96 + ci] = bf16_rne(cw[e]);
      return;
    }
    bx -= 1152;
    if (bx < 1248) {
      // wqkvT[l][half][kb(24)][n(208)][jj(8)] bf16
      int e = bx * 256 + t;                       // 319488
      int jj = e & 7, s8 = e >> 3;
      int n = s8 % 208, s9 = s8 / 208;
      int kb = s9 % 24, s10 = s9 / 24;            // s10 = l*2+half
      int half = s10 & 1, l = s10 >> 1;
      int k = kb * 8 + jj;
      float v;
      if (n < 96)       v = qk_w[(size_t)l * 36864 + (size_t)k * 192 + half * 96 + n];
      else if (n < 192) v = v_w [(size_t)l * 36864 + (size_t)k * 192 + half * 96 + n - 96];
      else if (n < 196) v = mass_w[(size_t)l * 1536 + (size_t)k * 8 + half * 4 + (n - 192)];
      else v = 0.f;
      wqkvT[e] = bf16_rne(v);
      return;
    }
    bx -= 1248;
    if (bx < 288) {
      // wm1T[kb(24)][n(384)][jj(8)]
      int e = bx * 256 + t;                       // 73728
      int jj = e & 7, s8 = e >> 3;
      int n = s8 % 384, kb = s8 / 384;
      wm1T[e] = bf16_rne(mlp_w1[(size_t)(kb * 8 + jj) * 384 + n]);
      return;
    }
    bx -= 288;
    {
      // wm2T[kb(48)][n(192)][jj(8)]
      int e = bx * 256 + t;                       // 73728
      int jj = e & 7, s8 = e >> 3;
      int n = s8 % 192, kb = s8 / 192;
      wm2T[e] = bf16_rne(mlp_w2[(size_t)(kb * 8 + jj) * 192 + n]);
      return;
    }
  }
  int wave = t >> 6, l = t & 63;
  size_t row = (size_t)bx * 4 + wave;
  const float* xr = x + row * 32;
  bool has2 = (l < 32);
  int c1 = l, c2 = has2 ? 64 + l : 0;
  float v1 = b[c1], v2 = b[c2];
  #pragma unroll
  for (int k = 0; k < 32; ++k) {
    float xv = xr[k];
    v1 += xv * w[k * 96 + c1];
    v2 += xv * w[k * 96 + c2];
  }
  if (!has2) v2 = 0.f;
  float sum = wave_sum(v1 + v2);
  float ssq = wave_sum(v1 * v1 + v2 * v2);
  sum = __shfl(sum, 0, 64); ssq = __shfl(ssq, 0, 64);
  float mu = sum / 96.f, var = ssq / 96.f - mu * mu;
  float inv = rsqrtf(var + 1e-5f);
  float f1 = gelu_f((v1 - mu) * inv * s[c1] + o[c1]);
  h0bf[row * 96 + c1] = bf16_rne(f1);
  if (has2) {
    float f2 = gelu_f((v2 - mu) * inv * s[c2] + o[c2]);
    h0bf[row * 96 + c2] = bf16_rne(f2);
  }
}

// ---------------- conv 4x4 SAME via 16 shifted MFMA GEMMs, bf16 weights
__global__ __launch_bounds__(256) void conv_kern(
    const unsigned short* __restrict__ h0bf, const unsigned short* __restrict__ cwT,
    const float* __restrict__ cb, float* __restrict__ y)
{
  __shared__ unsigned short As[12 * 64 * 8];
  __shared__ unsigned short Ws[12 * 64 * 8];
  int t = threadIdx.x;
  int i = blockIdx.x;
  int n0 = blockIdx.y * 64;
  int wave = t >> 6, lane = t & 63, quad = lane >> 4, l16 = lane & 15;
  f32x4 zero4 = {0.f, 0.f, 0.f, 0.f};
  f32x4 acc[4];
  #pragma unroll
  for (int nt = 0; nt < 4; ++nt) acc[nt] = zero4;
  for (int tap = 0; tap < 16; ++tap) {
    int kh = tap >> 2, kw = tap & 3;
    int si = i + kh - 1;
    if (si < 0 || si >= 128) continue;
    {
      int j = t & 63, g = t >> 6;
      int sj = j + kw - 1;
      bool ok = (sj >= 0 && sj < 64);
      #pragma unroll
      for (int q = 0; q < 3; ++q) {
        int kb = g + 4 * q;
        short8 v = {0,0,0,0,0,0,0,0};
        if (ok) v = *(const short8*)(h0bf + (size_t)(si * 64 + sj) * 96 + kb * 8);
        *(short8*)(As + (kb * 64 + j) * 8) = v;
      }
    }
    {
      int n = t & 63, g = t >> 6;
      #pragma unroll
      for (int q = 0; q < 3; ++q) {
        int kb = g + 4 * q;
        *(short8*)(Ws + (kb * 64 + n) * 8) =
            *(const short8*)(cwT + ((size_t)tap * 192 + n0 + n) * 96 + kb * 8);
      }
    }
    __syncthreads();
    #pragma unroll
    for (int ks = 0; ks < 3; ++ks) {
      int kbq = ks * 4 + quad;
      short8 a = *(const short8*)(As + (kbq * 64 + wave * 16 + l16) * 8);
      #pragma unroll
      for (int nt = 0; nt < 4; ++nt) {
        short8 b = *(const short8*)(Ws + (kbq * 64 + nt * 16 + l16) * 8);
        acc[nt] = __builtin_amdgcn_mfma_f32_16x16x32_bf16(a, b, acc[nt], 0, 0, 0);
      }
    }
    __syncthreads();
  }
  #pragma unroll
  for (int nt = 0; nt < 4; ++nt) {
    int col = n0 + nt * 16 + l16;
    float bv = cb[col];
    #pragma unroll
    for (int r = 0; r < 4; ++r) {
      int row = wave * 16 + quad * 4 + r;
      y[(size_t)(i * 64 + row) * 192 + col] = acc[nt][r] + bv;
    }
  }
}

// ---------------- LN(192)+gelu: one wave per row, no barriers
__global__ __launch_bounds__(256) void ln_act_kern(
    const float* __restrict__ y, const float* __restrict__ res,
    const float* __restrict__ s, const float* __restrict__ o,
    float* __restrict__ h32, unsigned short* __restrict__ hbf)
{
  int t = threadIdx.x, wave = t >> 6, l = t & 63;
  size_t base = ((size_t)blockIdx.x * 4 + wave) * 192;
  float v0 = y[base + l], v1 = y[base + 64 + l], v2 = y[base + 128 + l];
  if (res) { v0 += res[base + l]; v1 += res[base + 64 + l]; v2 += res[base + 128 + l]; }
  float sum = wave_sum(v0 + v1 + v2);
  float ssq = wave_sum(v0 * v0 + v1 * v1 + v2 * v2);
  sum = __shfl(sum, 0, 64); ssq = __shfl(ssq, 0, 64);
  float mu = sum * (1.f / 192.f);
  float var = ssq * (1.f / 192.f) - mu * mu;
  float inv = rsqrtf(var + 1e-5f);
  float f0 = gelu_f((v0 - mu) * inv * s[l] + o[l]);
  float f1 = gelu_f((v1 - mu) * inv * s[64 + l] + o[64 + l]);
  float f2 = gelu_f((v2 - mu) * inv * s[128 + l] + o[128 + l]);
  h32[base + l] = f0; h32[base + 64 + l] = f1; h32[base + 128 + l] = f2;
  hbf[base + l] = bf16_rne(f0); hbf[base + 64 + l] = bf16_rne(f1); hbf[base + 128 + l] = bf16_rne(f2);
}

// ---------------- fused per-layer: [LN+gelu prologue] -> qkv+mass GEMM ->
// QQ^T -> softmax -> AV.  grid = 256 blocks: (b = bx>>1, half = bx&1).
// LDS (dynamic 104448 B):
//   phase 1: A_bf @0 (24576), Wt @24576 (79872)
//   phase>=2: qk_lds @0, v_lds @16384, w_bf @32768, mm @65536, sq @66560
__global__ __launch_bounds__(256) void layer_attn(
    const unsigned short* __restrict__ hbf0,
    const float* __restrict__ att_prev, const float* __restrict__ res_prev,
    const float* __restrict__ ns, const float* __restrict__ no,
    const unsigned short* __restrict__ wq,     // [half][kb24][n208][8] bf16
    const float* __restrict__ qb, const float* __restrict__ vb,
    const float* __restrict__ mb,
    float* __restrict__ h32_out, float* __restrict__ att)
{
  extern __shared__ char smem[];
  unsigned short* A_bf = (unsigned short*)smem;               // [24kb][64m][8]
  unsigned short* Wt   = (unsigned short*)(smem + 24576);     // [24kb][208n][8]
  unsigned short* qk_lds = (unsigned short*)smem;             // [4h][4kb_d][64s][8]
  unsigned short* v_ldsp = (unsigned short*)(smem + 16384);   // [4h][8kb_s][32d][8]
  unsigned short* w_bfp  = (unsigned short*)(smem + 32768);   // [4h][8kb_sj][64si][8]
  float* mmp = (float*)(smem + 65536);                        // [64s][4h]
  float* sqp = (float*)(smem + 66560);                        // [4h][64]

  int t = threadIdx.x;
  int bb = blockIdx.x >> 1, half = blockIdx.x & 1;
  int wv = t >> 6, lane = t & 63, quad = lane >> 4, l16 = lane & 15;

  // ---- phase 0: build A (64x192 bf16) in LDS
  if (att_prev) {
    // fused LN+gelu of (att_prev + res_prev); 4 threads per row, 48 elems each
    int r = t >> 2, q = t & 3;
    size_t rbase = ((size_t)bb * 64 + r) * 192 + q * 48;
    f32x4 yv[12];
    float s1 = 0.f, s2 = 0.f;
    #pragma unroll
    for (int i = 0; i < 12; ++i) {
      f32x4 a4 = *(const f32x4*)(att_prev + rbase + i * 4);
      f32x4 r4 = *(const f32x4*)(res_prev + rbase + i * 4);
      f32x4 yy = a4 + r4;
      yv[i] = yy;
      #pragma unroll
      for (int c = 0; c < 4; ++c) { s1 += yy[c]; s2 += yy[c] * yy[c]; }
    }
    s1 += __shfl_xor(s1, 1, 64); s1 += __shfl_xor(s1, 2, 64);
    s2 += __shfl_xor(s2, 1, 64); s2 += __shfl_xor(s2, 2, 64);
    float mu = s1 * (1.f / 192.f);
    float inv = rsqrtf(s2 * (1.f / 192.f) - mu * mu + 1e-5f);
    #pragma unroll
    for (int i = 0; i < 12; ++i) {
      f32x4 sv = *(const f32x4*)(ns + q * 48 + i * 4);
      f32x4 ov = *(const f32x4*)(no + q * 48 + i * 4);
      f32x4 ff;
      #pragma unroll
      for (int c = 0; c < 4; ++c) ff[c] = gelu_f((yv[i][c] - mu) * inv * sv[c] + ov[c]);
      *(f32x4*)(h32_out + rbase + i * 4) = ff;   // both halves write same bits
      yv[i] = ff;
    }
    #pragma unroll
    for (int kb6 = 0; kb6 < 6; ++kb6) {
      short8 v8;
      #pragma unroll
      for (int c = 0; c < 4; ++c) {
        v8[c]     = (short)bf16_rne(yv[kb6 * 2][c]);
        v8[4 + c] = (short)bf16_rne(yv[kb6 * 2 + 1][c]);
      }
      *(short8*)(A_bf + ((q * 6 + kb6) * 64 + r) * 8) = v8;
    }
  } else {
    for (int c = t; c < 1536; c += 256) {
      int kb = c >> 6, m = c & 63;
      *(short8*)(A_bf + c * 8) =
          *(const short8*)(hbf0 + ((size_t)bb * 64 + m) * 192 + kb * 8);
    }
  }
  // ---- stage W (pre-converted, coalesced): 4992 short8 chunks
  {
    const unsigned short* wsrc = wq + (size_t)half * 39936;
    for (int c = t; c < 4992; c += 256)
      *(short8*)(Wt + c * 8) = *(const short8*)(wsrc + c * 8);
  }
  __syncthreads();

  // ---- phase 1: GEMM 64x208x192, single phase, 78 MFMA
  f32x4 acc[13];
  #pragma unroll
  for (int i = 0; i < 13; ++i) acc[i] = (f32x4){0.f,0.f,0.f,0.f};
  #pragma unroll
  for (int s = 0; s < 6; ++s) {
    int kq = s * 4 + quad;
    short8 a = *(const short8*)(A_bf + (kq * 64 + wv * 16 + l16) * 8);
    #pragma unroll
    for (int nt = 0; nt < 13; ++nt) {
      short8 b = *(const short8*)(Wt + (kq * 208 + nt * 16 + l16) * 8);
      acc[nt] = __builtin_amdgcn_mfma_f32_16x16x32_bf16(a, b, acc[nt], 0, 0, 0);
    }
  }
  __syncthreads();   // A_bf/Wt dead; regions reused below

  // ---- phase 2: scatter acc -> qk_lds (bf16, zero-pad d=24..31), v_lds, mass
  {
    int zh = t >> 6, zs = t & 63;
    *(short8*)(qk_lds + ((zh * 4 + 3) * 64 + zs) * 8) = (short8){0,0,0,0,0,0,0,0};
  }
  int row = wv * 16 + quad * 4;
  #pragma unroll
  for (int nt = 0; nt < 6; ++nt) {
    int n = nt * 16 + l16;
    int hl = n / 24, d = n - hl * 24;
    float bqv = qb[half * 96 + n];
    #pragma unroll
    for (int r = 0; r < 4; ++r)
      qk_lds[((hl * 4 + (d >> 3)) * 64 + row + r) * 8 + (d & 7)] =
          bf16_rne(acc[nt][r] + bqv);
  }
  #pragma unroll
  for (int nt = 0; nt < 6; ++nt) {
    int n = nt * 16 + l16;
    int hl = n / 24, d = n - hl * 24;
    float bvv = vb[half * 96 + n];
    #pragma unroll
    for (int r = 0; r < 4; ++r) {
      int sidx = row + r;
      v_ldsp[((hl * 8 + (sidx >> 3)) * 32 + d) * 8 + (sidx & 7)] =
          bf16_rne(acc[nt + 6][r] + bvv);
    }
  }
  if (l16 < 4) {
    float mbv = mb[half * 4 + l16];
    #pragma unroll
    for (int r = 0; r < 4; ++r)
      mmp[(row + r) * 4 + l16] = softplus_f(acc[12][r] + mbv);
  }
  __syncthreads();

  // ---- phase 3: per-wave head: S = QQ^T (K=24 pad 32), scores, softmax in regs
  const unsigned short* qh = qk_lds + (wv * 4) * 64 * 8;
  short8 frag[4];
  #pragma unroll
  for (int x2 = 0; x2 < 4; ++x2)
    frag[x2] = *(const short8*)(qh + (quad * 64 + x2 * 16 + l16) * 8);
  f32x4 s16[4][4];
  #pragma unroll
  for (int mt = 0; mt < 4; ++mt)
    #pragma unroll
    for (int nt = 0; nt < 4; ++nt)
      s16[mt][nt] = __builtin_amdgcn_mfma_f32_16x16x32_bf16(
          frag[mt], frag[nt], (f32x4){0.f,0.f,0.f,0.f}, 0, 0, 0);
  float* sqh = sqp + wv * 64;
  #pragma unroll
  for (int mt = 0; mt < 4; ++mt)
    #pragma unroll
    for (int r = 0; r < 4; ++r)
      if (l16 == quad * 4 + r) sqh[mt * 16 + l16] = s16[mt][mt][r];
  __syncthreads();
  f32x4 sqr[4], mr[4];
  float sqc[4], mc[4];
  #pragma unroll
  for (int mt = 0; mt < 4; ++mt) {
    sqr[mt] = *(const f32x4*)(sqh + mt * 16 + quad * 4);
    #pragma unroll
    for (int r = 0; r < 4; ++r) mr[mt][r] = mmp[(mt * 16 + quad * 4 + r) * 4 + wv];
  }
  #pragma unroll
  for (int nt = 0; nt < 4; ++nt) {
    sqc[nt] = sqh[nt * 16 + l16];
    mc[nt]  = mmp[(nt * 16 + l16) * 4 + wv];
  }
  #pragma unroll
  for (int mt = 0; mt < 4; ++mt)
    #pragma unroll
    for (int nt = 0; nt < 4; ++nt)
      #pragma unroll
      for (int r = 0; r < 4; ++r) {
        float d2 = fmaxf(sqr[mt][r] + sqc[nt] - 2.f * s16[mt][nt][r], 0.f) + 1e-6f;
        s16[mt][nt][r] = mr[mt][r] * mc[nt] / d2;
      }
  f32x4 inv4[4];
  #pragma unroll
  for (int mt = 0; mt < 4; ++mt)
    #pragma unroll
    for (int r = 0; r < 4; ++r) {
      float mx = fmaxf(fmaxf(s16[mt][0][r], s16[mt][1][r]),
                       fmaxf(s16[mt][2][r], s16[mt][3][r]));
      #pragma unroll
      for (int off = 1; off < 16; off <<= 1) mx = fmaxf(mx, __shfl_xor(mx, off, 64));
      float sm = 0.f;
      #pragma unroll
      for (int nt = 0; nt < 4; ++nt) {
        float e = __expf(s16[mt][nt][r] - mx);
        s16[mt][nt][r] = e;
        sm += e;
      }
      #pragma unroll
      for (int off = 1; off < 16; off <<= 1) sm += __shfl_xor(sm, off, 64);
      inv4[mt][r] = 1.f / sm;
    }

  // ---- phase 4: P (bf16) -> LDS in AV A-operand layout
  unsigned short* wb = w_bfp + wv * (8 * 64 * 8);
  #pragma unroll
  for (int mt = 0; mt < 4; ++mt)
    #pragma unroll
    for (int nt = 0; nt < 4; ++nt)
      #pragma unroll
      for (int r = 0; r < 4; ++r) {
        int si = mt * 16 + quad * 4 + r, sj = nt * 16 + l16;
        wb[((sj >> 3) * 64 + si) * 8 + (sj & 7)] = bf16_rne(s16[mt][nt][r]);
      }
  __syncthreads();

  // ---- phase 5: O = P @ V (K=64), scale by 1/rowsum, store
  const unsigned short* vh = v_ldsp + wv * (8 * 32 * 8);
  f32x4 o2[4][2];
  #pragma unroll
  for (int mt = 0; mt < 4; ++mt)
    #pragma unroll
    for (int nt = 0; nt < 2; ++nt) o2[mt][nt] = (f32x4){0.f,0.f,0.f,0.f};
  #pragma unroll
  for (int ks = 0; ks < 2; ++ks) {
    int kq = ks * 4 + quad;
    short8 aw[4], bv2[2];
    #pragma unroll
    for (int mt = 0; mt < 4; ++mt)
      aw[mt] = *(const short8*)(wb + (kq * 64 + mt * 16 + l16) * 8);
    #pragma unroll
    for (int nt = 0; nt < 2; ++nt)
      bv2[nt] = *(const short8*)(vh + (kq * 32 + nt * 16 + l16) * 8);
    #pragma unroll
    for (int mt = 0; mt < 4; ++mt)
      #pragma unroll
      for (int nt = 0; nt < 2; ++nt)
        o2[mt][nt] = __builtin_amdgcn_mfma_f32_16x16x32_bf16(aw[mt], bv2[nt], o2[mt][nt], 0, 0, 0);
  }
  int hg = half * 4 + wv;
  size_t obase = ((size_t)bb * 64) * 192 + hg * 24;
  #pragma unroll
  for (int mt = 0; mt < 4; ++mt)
    #pragma unroll
    for (int nt = 0; nt < 2; ++nt) {
      int col = nt * 16 + l16;
      if (col < 24) {
        #pragma unroll
        for (int r = 0; r < 4; ++r) {
          int sidx = mt * 16 + quad * 4 + r;
          att[obase + (size_t)sidx * 192 + col] = o2[mt][nt][r] * inv4[mt][r];
        }
      }
    }
}

// ---------------- small MFMA GEMM with pre-converted bf16 weights
__global__ __launch_bounds__(256) void gemm_smallT(
    const unsigned short* __restrict__ A, int lda,
    const unsigned short* __restrict__ WT, int nld,
    const float* __restrict__ bias, const float* __restrict__ res,
    float* __restrict__ outF, unsigned short* __restrict__ outB,
    int K, int ldo, int act)
{
  __shared__ unsigned short As[8 * 64 * 8];
  __shared__ unsigned short Ws[8 * 64 * 8];
  int t = threadIdx.x;
  int m0 = blockIdx.x * 64, n0 = blockIdx.y * 64;
  int wave = t >> 6, lane = t & 63, quad = lane >> 4, l16 = lane & 15;
  f32x4 zero4 = {0.f, 0.f, 0.f, 0.f};
  f32x4 acc[4];
  #pragma unroll
  for (int nt = 0; nt < 4; ++nt) acc[nt] = zero4;
  for (int k0 = 0; k0 < K; k0 += 64) {
    {
      int kb = t & 7, m = t >> 3;
      #pragma unroll
      for (int r = 0; r < 2; ++r) {
        int mm = m + r * 32;
        *(short8*)(As + (kb * 64 + mm) * 8) =
            *(const short8*)(A + (size_t)(m0 + mm) * lda + k0 + kb * 8);
      }
    }
    {
      int kbase = k0 >> 3;
      #pragma unroll
      for (int cc = 0; cc < 2; ++cc) {
        int c = t + cc * 256;
        int kb = c >> 6, nn = c & 63;
        *(short8*)(Ws + c * 8) =
            *(const short8*)(WT + ((size_t)(kbase + kb) * nld + n0 + nn) * 8);
      }
    }
    __syncthreads();
    #pragma unroll
    for (int ks = 0; ks < 2; ++ks) {
      short8 a = *(const short8*)(As + ((ks * 4 + quad) * 64 + wave * 16 + l16) * 8);
      #pragma unroll
      for (int nt = 0; nt < 4; ++nt) {
        short8 b = *(const short8*)(Ws + ((ks * 4 + quad) * 64 + nt * 16 + l16) * 8);
        acc[nt] = __builtin_amdgcn_mfma_f32_16x16x32_bf16(a, b, acc[nt], 0, 0, 0);
      }
    }
    __syncthreads();
  }
  #pragma unroll
  for (int nt = 0; nt < 4; ++nt) {
    int col = n0 + nt * 16 + l16;
    float bv = bias[col];
    #pragma unroll
    for (int r = 0; r < 4; ++r) {
      int row = m0 + wave * 16 + quad * 4 + r;
      float v = acc[nt][r] + bv;
      if (act) v = gelu_f(v);
      if (res) v += res[(size_t)row * ldo + col];
      if (outF) outF[(size_t)row * ldo + col] = v;
      if (outB) outB[(size_t)row * ldo + col] = bf16_rne(v);
    }
  }
}

// ---------------- fc: (128 x 12288) @ (12288 x 12288), split-K=4, BN=64
// Double-buffered LDS + reg prefetch: 1 barrier/iter, 2 tiles in flight.
__global__ __launch_bounds__(256) void gemm_fc(
    const unsigned short* __restrict__ A, const float* __restrict__ W,
    float* __restrict__ part)
{
  __shared__ unsigned short As[2][8 * 128 * 8];   // 2 x 16 KB
  __shared__ unsigned short Bs[2][8 * 64 * 8];    // 2 x 8 KB
  int t = threadIdx.x;
  int n0 = blockIdx.x * 64;
  int split = blockIdx.y;
  int wave = t >> 6, lane = t & 63, quad = lane >> 4, l16 = lane & 15;
  int wm = wave * 32;
  int a_kb = t & 7, a_m = t >> 3;
  int w_n4 = t & 15, w_kr = t >> 4;
  f32x4 zero4 = {0.f, 0.f, 0.f, 0.f};
  f32x4 acc[2][4];
  #pragma unroll
  for (int mt = 0; mt < 2; ++mt)
    #pragma unroll
    for (int nt = 0; nt < 4; ++nt) acc[mt][nt] = zero4;
  int kk = split * 3072;
  short8 aR[4]; f32x4 wR[4];
  // load tile 0
  #pragma unroll
  for (int r = 0; r < 4; ++r)
    aR[r] = *(const short8*)(A + (size_t)(a_m + r * 32) * 12288 + kk + a_kb * 8);
  #pragma unroll
  for (int r = 0; r < 4; ++r)
    wR[r] = *(const f32x4*)(W + (size_t)(kk + w_kr + 16 * r) * 12288 + n0 + w_n4 * 4);
  // store tile 0 -> buf 0
  #pragma unroll
  for (int r = 0; r < 4; ++r)
    *(short8*)(As[0] + (a_kb * 128 + a_m + r * 32) * 8) = aR[r];
  #pragma unroll
  for (int r = 0; r < 4; ++r) {
    int k = w_kr + 16 * r, kb = k >> 3, kj = k & 7;
    #pragma unroll
    for (int j = 0; j < 4; ++j)
      Bs[0][(kb * 64 + w_n4 * 4 + j) * 8 + kj] = bf16_rne(wR[r][j]);
  }
  // load tile 1
  #pragma unroll
  for (int r = 0; r < 4; ++r)
    aR[r] = *(const short8*)(A + (size_t)(a_m + r * 32) * 12288 + kk + 64 + a_kb * 8);
  #pragma unroll
  for (int r = 0; r < 4; ++r)
    wR[r] = *(const f32x4*)(W + (size_t)(kk + 64 + w_kr + 16 * r) * 12288 + n0 + w_n4 * 4);
  __syncthreads();
  for (int it = 0; it < 48; ++it) {
    int buf = it & 1;
    if (it < 47) {
      // store regs (tile it+1) -> buf^1
      #pragma unroll
      for (int r = 0; r < 4; ++r)
        *(short8*)(As[buf ^ 1] + (a_kb * 128 + a_m + r * 32) * 8) = aR[r];
      #pragma unroll
      for (int r = 0; r < 4; ++r) {
        int k = w_kr + 16 * r, kb = k >> 3, kj = k & 7;
        #pragma unroll
        for (int j = 0; j < 4; ++j)
          Bs[buf ^ 1][(kb * 64 + w_n4 * 4 + j) * 8 + kj] = bf16_rne(wR[r][j]);
      }
    }
    if (it < 46) {
      int kn = kk + (it + 2) * 64;
      #pragma unroll
      for (int r = 0; r < 4; ++r)
        aR[r] = *(const short8*)(A + (size_t)(a_m + r * 32) * 12288 + kn + a_kb * 8);
      #pragma unroll
      for (int r = 0; r < 4; ++r)
        wR[r] = *(const f32x4*)(W + (size_t)(kn + w_kr + 16 * r) * 12288 + n0 + w_n4 * 4);
    }
    #pragma unroll
    for (int ks = 0; ks < 2; ++ks) {
      int kq = ks * 4 + quad;
      short8 a[2], b[4];
      #pragma unroll
      for (int mt = 0; mt < 2; ++mt)
        a[mt] = *(const short8*)(As[buf] + (kq * 128 + wm + mt * 16 + l16) * 8);
      #pragma unroll
      for (int nt = 0; nt < 4; ++nt)
        b[nt] = *(const short8*)(Bs[buf] + (kq * 64 + nt * 16 + l16) * 8);
      #pragma unroll
      for (int mt = 0; mt < 2; ++mt)
        #pragma unroll
        for (int nt = 0; nt < 4; ++nt)
          acc[mt][nt] = __builtin_amdgcn_mfma_f32_16x16x32_bf16(a[mt], b[nt], acc[mt][nt], 0, 0, 0);
    }
    __syncthreads();
  }
  float* po = part + (size_t)split * 128 * 12288;
  #pragma unroll
  for (int mt = 0; mt < 2; ++mt) {
    #pragma unroll
    for (int nt = 0; nt < 4; ++nt) {
      int col = n0 + nt * 16 + l16;
      #pragma unroll
      for (int r = 0; r < 4; ++r) {
        int row = wm + mt * 16 + quad * 4 + r;
        po[(size_t)row * 12288 + col] = acc[mt][nt][r];
      }
    }
  }
}

// ---------------- fused: split-K reduce + bias + gelu -> LDS -> LN(12288) -> out matmul
__global__ __launch_bounds__(256) void final_kern(
    const float* __restrict__ part, const float* __restrict__ fb,
    const float* __restrict__ s, const float* __restrict__ o,
    const float* __restrict__ ow, const float* __restrict__ ob,
    float* __restrict__ out)
{
  __shared__ float gls[12288];                  // 48 KB
  __shared__ float a1[4], a2[4];
  __shared__ float red[4][24];
  int m = blockIdx.x, t = threadIdx.x;
  const f32x4* p0 = (const f32x4*)(part + (size_t)m * 12288);
  const size_t S4 = (size_t)128 * 12288 / 4;
  float s1 = 0.f, s2 = 0.f;
  for (int k4 = t; k4 < 3072; k4 += 256) {
    f32x4 v = p0[k4] + p0[k4 + S4] + p0[k4 + 2 * S4] + p0[k4 + 3 * S4];
    f32x4 bb = *(const f32x4*)(fb + k4 * 4);
    f32x4 g;
    #pragma unroll
    for (int c = 0; c < 4; ++c) g[c] = gelu_f(v[c] + bb[c]);
    *(f32x4*)(gls + k4 * 4) = g;
    s1 += g[0] + g[1] + g[2] + g[3];
    s2 += g[0]*g[0] + g[1]*g[1] + g[2]*g[2] + g[3]*g[3];
  }
  s1 = wave_sum(s1); s2 = wave_sum(s2);
  int wv = t >> 6, ln = t & 63;
  if (ln == 0) { a1[wv] = s1; a2[wv] = s2; }
  __syncthreads();
  float sum = a1[0] + a1[1] + a1[2] + a1[3];
  float ssq = a2[0] + a2[1] + a2[2] + a2[3];
  float mu = sum / 12288.f, var = ssq / 12288.f - mu * mu;
  float inv = rsqrtf(var + 1e-5f);
  f32x4 acc6[6];
  #pragma unroll
  for (int j = 0; j < 6; ++j) acc6[j] = (f32x4){0.f,0.f,0.f,0.f};
  for (int k = t; k < 12288; k += 256) {
    float f = (gls[k] - mu) * inv * s[k] + o[k];
    const f32x4* owr = (const f32x4*)(ow + (size_t)k * 24);
    #pragma unroll
    for (int j = 0; j < 6; ++j) acc6[j] += f * owr[j];
  }
  #pragma unroll
  for (int j = 0; j < 6; ++j)
    #pragma unroll
    for (int c = 0; c < 4; ++c) {
      float v = wave_sum(acc6[j][c]);
      if (ln == 0) red[wv][j * 4 + c] = v;
    }
  __syncthreads();
  if (t < 24) out[m * 24 + t] = red[0][t] + red[1][t] + red[2][t] + red[3][t] + ob[t];
}

extern "C" void kernel_launch(void* const* d_in, const int* in_sizes, int n_in,
                              void* d_out, int out_size, void* d_ws, size_t ws_size,
                              hipStream_t stream) {
  const float* x      = (const float*)d_in[0];
  const float* proj_w = (const float*)d_in[1];
  const float* proj_b = (const float*)d_in[2];
  const float* ln0_s  = (const float*)d_in[3];
  const float* ln0_o  = (const float*)d_in[4];
  const float* conv_w = (const float*)d_in[5];
  const float* conv_b = (const float*)d_in[6];
  const float* ln1_s  = (const float*)d_in[7];
  const float* ln1_o  = (const float*)d_in[8];
  const float* qk_w   = (const float*)d_in[9];
  const float* qk_b   = (const float*)d_in[10];
  const float* mass_w = (const float*)d_in[11];
  const float* mass_b = (const float*)d_in[12];
  const float* v_w    = (const float*)d_in[13];
  const float* v_b    = (const float*)d_in[14];
  const float* norm_s = (const float*)d_in[15];
  const float* norm_o = (const float*)d_in[16];
  const float* mlp_w1 = (const float*)d_in[17];
  const float* mlp_b1 = (const float*)d_in[18];
  const float* mlp_w2 = (const float*)d_in[19];
  const float* mlp_b2 = (const float*)d_in[20];
  const float* fc_w   = (const float*)d_in[21];
  const float* fc_b   = (const float*)d_in[22];
  const float* ln2_s  = (const float*)d_in[23];
  const float* ln2_o  = (const float*)d_in[24];
  const float* out_w  = (const float*)d_in[25];
  const float* out_b  = (const float*)d_in[26];
  float* out = (float*)d_out;

  char* ws = (char*)d_ws;
  unsigned short* h0bf  = (unsigned short*)(ws + 0);            // 1,572,864
  unsigned short* hbf   = (unsigned short*)(ws + 1572864);      // 3,145,728
  unsigned short* cwT   = (unsigned short*)(ws + 4718592);      // 589,824
  unsigned short* wqkvT = (unsigned short*)(ws + 5308416);      // 638,976
  unsigned short* wm1T  = (unsigned short*)(ws + 5947392);      // 147,456
  unsigned short* wm2T  = (unsigned short*)(ws + 6094848);      // 147,456
  float* h32a = (float*)(ws + 6242304);                         // 6,291,456
  float* h32b = (float*)(ws + 12533760);                        // 6,291,456
  float* tA   = (float*)(ws + 18825216);                        // 6,291,456
  float* tB   = (float*)(ws + 25116672);                        // 6,291,456
  unsigned short* hid_bf = (unsigned short*)(ws + 31408128);    // 6,291,456
  float* partials = (float*)(ws + 37699584);                    // 25,165,824

  pre_kern<<<5024, 256, 0, stream>>>(x, proj_w, proj_b, ln0_s, ln0_o, h0bf,
      conv_w, cwT, qk_w, v_w, mass_w, wqkvT, mlp_w1, wm1T, mlp_w2, wm2T);
  conv_kern<<<dim3(128, 3), 256, 0, stream>>>(h0bf, cwT, conv_b, tB);
  ln_act_kern<<<2048, 256, 0, stream>>>(tB, nullptr, ln1_s, ln1_o, h32a, hbf);
  // layer 0: A from hbf (h0)
  layer_attn<<<256, 256, 104448, stream>>>(hbf, nullptr, nullptr, nullptr, nullptr,
      wqkvT + 0 * 79872, qk_b + 0, v_b + 0, mass_b + 0, nullptr, tA);
  // layer 1: LN(att0 + h0, norm0) -> h1(h32b); out att1 -> tB
  layer_attn<<<256, 256, 104448, stream>>>(nullptr, tA, h32a, norm_s + 0, norm_o + 0,
      wqkvT + 1 * 79872, qk_b + 192, v_b + 192, mass_b + 8, h32b, tB);
  // layer 2: LN(att1 + h1, norm1) -> h2(h32a); out att2 -> tA
  layer_attn<<<256, 256, 104448, stream>>>(nullptr, tB, h32b, norm_s + 192, norm_o + 192,
      wqkvT + 2 * 79872, qk_b + 384, v_b + 384, mass_b + 16, h32a, tA);
  // layer 3: LN(att2 + h2, norm2) -> h3(h32b); out att3 -> tB
  layer_attn<<<256, 256, 104448, stream>>>(nullptr, tA, h32a, norm_s + 384, norm_o + 384,
      wqkvT + 3 * 79872, qk_b + 576, v_b + 576, mass_b + 24, h32b, tB);
  // final LN of layer 3 output: h4 -> h32a + hbf
  ln_act_kern<<<2048, 256, 0, stream>>>(tB, h32b, norm_s + 576, norm_o + 576, h32a, hbf);
  gemm_smallT<<<dim3(128, 6), 256, 0, stream>>>(hbf, 192, wm1T, 384, mlp_b1,
      nullptr, (float*)nullptr, hid_bf, 192, 384, 1);
  gemm_smallT<<<dim3(128, 3), 256, 0, stream>>>(hid_bf, 384, wm2T, 192, mlp_b2,
      h32a, (float*)nullptr, hbf, 384, 192, 0);
  gemm_fc<<<dim3(192, 4), 256, 0, stream>>>(hbf, fc_w, partials);
  final_kern<<<128, 256, 0, stream>>>(partials, fc_b, ln2_s, ln2_o, out_w, out_b, out);
}